// Round 14
// baseline (4308.368 us; speedup 1.0000x reference)
//
#include <hip/hip_runtime.h>
#include <hip/hip_bf16.h>
#include <math.h>

// CaloClusterNet: 4-layer edge/node MPNN, H=96, bf16 compute, fp32 accumulate.
// Round 14: (1) edge_layer __launch_bounds__(512,6) caps VGPR (<~85) so the
// 44KB-LDS kernel actually reaches 3 blk/CU = 24 waves (R13 hit a 128-VGPR
// wall = same 16 waves as R12). (2) head_kernel swapped-GEMM rewrite: row-local
// epilogue, 8B vector gathers, 2-shuffle reduction (was 192 scalar loads + 16
// shuffles per row-quad; measured 180us at 1.1TB/s, 38% VALU).

typedef __attribute__((ext_vector_type(8))) short short8;
typedef __attribute__((ext_vector_type(4))) float f32x4;

#define MFMA(a, b, c) __builtin_amdgcn_mfma_f32_16x16x32_bf16((a), (b), (c), 0, 0, 0)
#define WSTR 112  // LDS row stride in ushorts (224B, 16B-aligned)

__device__ __forceinline__ float bf2f(ushort u) {
    union { uint i; float f; } v; v.i = ((uint)u) << 16; return v.f;
}
__device__ __forceinline__ ushort f2bf(float f) {
    union { float f; uint i; } v; v.f = f;
    uint b = v.i;
    return (ushort)((b + 0x7FFFu + ((b >> 16) & 1u)) >> 16);  // RNE
}
__device__ __forceinline__ float gelu_f(float x) {
    return 0.5f * x * (1.0f + erff(x * 0.70710678118654752440f));
}
__device__ __forceinline__ short8 ld8(const ushort* p) { return *(const short8*)p; }
__device__ __forceinline__ ushort cvt_elem(const void* p, size_t j, int f32) {
    return f32 ? f2bf(((const float*)p)[j]) : ((const ushort*)p)[j];
}
template <int NT>
__device__ __forceinline__ void stageW(ushort* dst, const ushort* src, int t) {
    for (int i = t; i < 1152; i += NT) {
        int row = i / 12, ch = i - row * 12;
        ((short8*)dst)[row * 14 + ch] = ((const short8*)src)[i];
    }
}

// ---------------- dtype detector ----------------
__global__ __launch_bounds__(256) void detect_kernel(
    const ushort* __restrict__ X, const uint* __restrict__ IDX, int* __restrict__ flags)
{
    __shared__ int cnt[2];
    if (threadIdx.x == 0) { cnt[0] = 0; cnt[1] = 0; }
    __syncthreads();
    int plaus = 0;
    for (int i = threadIdx.x; i < 2048; i += 256) {
        float v = fabsf(bf2f(X[i]));
        if (v > 1e-3f && v < 100.f) plaus++;
    }
    atomicAdd(&cnt[0], plaus);
    int nz = 0;
    for (int i = threadIdx.x; i < 1024; i += 256)
        if (IDX[2 * i + 1] != 0) nz++;
    atomicAdd(&cnt[1], nz);
    __syncthreads();
    if (threadIdx.x == 0) {
        flags[0] = (cnt[0] < 1843) ? 1 : 0;  // fp32 if <90% plausible as bf16
        flags[1] = (cnt[1] == 0) ? 1 : 0;    // int64 if all high words zero
    }
}

// ---------------- small arrays -> bf16 ----------------
struct SPk { const void* src[16]; int off[17]; };
__global__ __launch_bounds__(256) void smalls_kernel(SPk p, ushort* __restrict__ dst,
                                                     const int* __restrict__ flags) {
    int f = flags[0];
    for (int i = threadIdx.x; i < 3650; i += 256) {
        int e = 0;
        while (e < 15 && i >= p.off[e + 1]) e++;
        dst[i] = cvt_elem(p.src[e], (size_t)(i - p.off[e]), f);
    }
}

// ---------------- weight transpose: 34 96x96 matrices -> bf16 ----------------
struct TPk { const void* base[34]; int eloff[34]; };
__global__ __launch_bounds__(256) void transpose_k(TPk p, ushort* __restrict__ dst,
                                                   const int* __restrict__ flags) {
    int f = flags[0];
    int m = blockIdx.x;
    const void* s = p.base[m];
    size_t off = (size_t)p.eloff[m];
    ushort* d = dst + (size_t)m * 9216;
    for (int i = threadIdx.x; i < 9216; i += 256) {
        int n = i / 96, k = i - n * 96;      // d[n*96+k] = s[k*96+n]
        d[i] = cvt_elem(s, off + (size_t)k * 96 + n, f);
    }
}

// ---------------- index canonicalization -> int32 ----------------
__global__ __launch_bounds__(256) void idx_convert(
    const int* __restrict__ eidx, int* __restrict__ s32, int* __restrict__ d32,
    const int* __restrict__ flags, int E)
{
    int f = flags[1];
    for (size_t i = (size_t)blockIdx.x * 256 + threadIdx.x; i < (size_t)E;
         i += (size_t)gridDim.x * 256) {
        s32[i] = f ? eidx[2 * i] : eidx[i];
        d32[i] = f ? eidx[2 * ((size_t)E + i)] : eidx[(size_t)E + i];
    }
}

// ---------------- x / edge_attr canonicalization -> bf16 ----------------
__global__ __launch_bounds__(256) void xe_convert(
    const void* __restrict__ xin, const void* __restrict__ ein,
    ushort* __restrict__ xb, ushort* __restrict__ eb,
    const int* __restrict__ flags, size_t nx, size_t ne)
{
    int f = flags[0];
    size_t total = nx + ne;
    for (size_t i = (size_t)blockIdx.x * 256 + threadIdx.x; i < total;
         i += (size_t)gridDim.x * 256) {
        if (i < nx) xb[i] = cvt_elem(xin, i, f);
        else        eb[i - nx] = cvt_elem(ein, i - nx, f);
    }
}

// ---------------- counting sort by dst: hist -> prefix -> scatter ----------------
__global__ __launch_bounds__(256) void hist_kernel(const int* __restrict__ d32,
                                                   int* __restrict__ cnt, int E) {
    for (size_t i = (size_t)blockIdx.x * 256 + threadIdx.x; i < (size_t)E;
         i += (size_t)gridDim.x * 256)
        atomicAdd(&cnt[d32[i]], 1);
}

__global__ __launch_bounds__(1024) void prefix_kernel(int* __restrict__ cnt,
                                                      int* __restrict__ rowptr,
                                                      int N, int E) {
    __shared__ int part[1024];
    int t = threadIdx.x;
    int chunk = (N + 1023) / 1024;
    int b = t * chunk, e = b + chunk; if (e > N) e = N;
    int s = 0;
    for (int i = b; i < e; i++) s += cnt[i];
    part[t] = s;
    __syncthreads();
    for (int off = 1; off < 1024; off <<= 1) {
        int v = (t >= off) ? part[t - off] : 0;
        __syncthreads();
        part[t] += v;
        __syncthreads();
    }
    int run = part[t] - s;  // exclusive prefix
    for (int i = b; i < e; i++) {
        int c = cnt[i];
        rowptr[i] = run;
        cnt[i] = run;       // reuse cnt as scatter cursor
        run += c;
    }
    if (t == 1023) rowptr[N] = E;
}

__global__ __launch_bounds__(256) void scatter_kernel(
    const int* __restrict__ s32, const int* __restrict__ d32,
    int* __restrict__ cursor, int* __restrict__ ss, int* __restrict__ ds,
    int* __restrict__ eid, int E)
{
    for (size_t i = (size_t)blockIdx.x * 256 + threadIdx.x; i < (size_t)E;
         i += (size_t)gridDim.x * 256) {
        int d = d32[i];
        int pos = atomicAdd(&cursor[d], 1);
        ss[pos] = s32[i];
        ds[pos] = d;
        eid[pos] = (int)i;
    }
}

// ---------------- encoder (optional row-gather via EID for sorted e) ----------------
template <int K, bool WF32>
__global__ __launch_bounds__(256) void encoder_kernel(
    const ushort* __restrict__ X, const ushort* __restrict__ W1,
    const ushort* __restrict__ B1, const ushort* __restrict__ W2t,
    const ushort* __restrict__ B2, ushort* __restrict__ OutB,
    float* __restrict__ OutF, const int* __restrict__ EID, int R)
{
    __shared__ __align__(16) ushort sW2[96 * WSTR];
    __shared__ float sW1[K * 96];
    __shared__ float sb1[96], sb2[96];
    __shared__ __align__(16) ushort gscr[4][16 * WSTR];
    int t = threadIdx.x;
    stageW<256>(sW2, W2t, t);
    for (int i = t; i < K * 96; i += 256) sW1[i] = bf2f(W1[i]);
    if (t < 96) { sb1[t] = bf2f(B1[t]); sb2[t] = bf2f(B2[t]); }
    __syncthreads();

    const int wave = t >> 6, lane = t & 63, lr = lane & 15, cg = lane >> 4, lk = cg * 8;
    int rbase = blockIdx.x * 64 + wave * 16;

    float wf[K][6];
#pragma unroll
    for (int k = 0; k < K; k++)
#pragma unroll
        for (int n = 0; n < 6; n++) wf[k][n] = sW1[k * 96 + n * 16 + lr];

    ushort* g = gscr[wave];
#pragma unroll
    for (int j = 0; j < 4; j++) {
        int r = rbase + cg * 4 + j;
        int rc = r < R ? r : R - 1;
        int rx = EID ? EID[rc] : rc;
        float xr[K];
        const uint* xu = (const uint*)(X + (size_t)rx * K);
#pragma unroll
        for (int q = 0; q < K / 2; q++) {
            uint u = xu[q];
            xr[2 * q] = bf2f((ushort)u); xr[2 * q + 1] = bf2f((ushort)(u >> 16));
        }
#pragma unroll
        for (int n = 0; n < 6; n++) {
            float v = sb1[n * 16 + lr];
#pragma unroll
            for (int k = 0; k < K; k++) v += xr[k] * wf[k][n];
            g[(cg * 4 + j) * WSTR + n * 16 + lr] = f2bf(gelu_f(v));
        }
    }
    __syncthreads();

    const ushort* grow = g + lr * WSTR + lk;
    short8 a0 = ld8(grow), a1 = ld8(grow + 32), a2 = ld8(grow + 64);
    f32x4 acc[6];
#pragma unroll
    for (int n = 0; n < 6; n++) {
        f32x4 z = {0.f, 0.f, 0.f, 0.f}; acc[n] = z;
        const ushort* wb = sW2 + (n * 16 + lr) * WSTR + lk;
        acc[n] = MFMA(a0, ld8(wb), acc[n]);
        acc[n] = MFMA(a1, ld8(wb + 32), acc[n]);
        acc[n] = MFMA(a2, ld8(wb + 64), acc[n]);
    }
#pragma unroll
    for (int j = 0; j < 4; j++) {
        int r = rbase + cg * 4 + j;
        if (r < R) {
#pragma unroll
            for (int n = 0; n < 6; n++) {
                int c = n * 16 + lr;
                float v = acc[n][j] + sb2[c];
                OutB[(size_t)r * 96 + c] = f2bf(v);
                if constexpr (WF32) OutF[(size_t)r * 96 + c] = v;
            }
        }
    }
}

// ---------------- dual GEMM ----------------
__global__ __launch_bounds__(256) void gemm_dual_kernel(
    const ushort* __restrict__ A, const ushort* __restrict__ W1t,
    const ushort* __restrict__ W2t, ushort* __restrict__ O1,
    ushort* __restrict__ O2, int R)
{
    __shared__ __align__(16) ushort sW1[96 * WSTR], sW2[96 * WSTR];
    int t = threadIdx.x;
    stageW<256>(sW1, W1t, t);
    stageW<256>(sW2, W2t, t);
    __syncthreads();
    const int wave = t >> 6, lane = t & 63, lr = lane & 15, cg = lane >> 4, lk = cg * 8;
    int rbase = blockIdx.x * 64 + wave * 16;
    int ra = rbase + lr; if (ra > R - 1) ra = R - 1;
    const ushort* arow = A + (size_t)ra * 96 + lk;
    short8 a0 = ld8(arow), a1 = ld8(arow + 32), a2 = ld8(arow + 64);
    f32x4 acc1[6], acc2[6];
#pragma unroll
    for (int n = 0; n < 6; n++) {
        f32x4 z = {0.f, 0.f, 0.f, 0.f}; acc1[n] = z; acc2[n] = z;
        const ushort* w1 = sW1 + (n * 16 + lr) * WSTR + lk;
        const ushort* w2 = sW2 + (n * 16 + lr) * WSTR + lk;
        acc1[n] = MFMA(a0, ld8(w1), acc1[n]);
        acc1[n] = MFMA(a1, ld8(w1 + 32), acc1[n]);
        acc1[n] = MFMA(a2, ld8(w1 + 64), acc1[n]);
        acc2[n] = MFMA(a0, ld8(w2), acc2[n]);
        acc2[n] = MFMA(a1, ld8(w2 + 32), acc2[n]);
        acc2[n] = MFMA(a2, ld8(w2 + 64), acc2[n]);
    }
#pragma unroll
    for (int j = 0; j < 4; j++) {
        int r = rbase + cg * 4 + j;
        if (r < R) {
#pragma unroll
            for (int n = 0; n < 6; n++) {
                int c = n * 16 + lr;
                O1[(size_t)r * 96 + c] = f2bf(acc1[n][j]);
                O2[(size_t)r * 96 + c] = f2bf(acc2[n][j]);
            }
        }
    }
}

// ---- fused edge layer: swapped GEMM1 + shuffle transpose; VGPR-capped ----
__global__ __launch_bounds__(512, 6) void edge_layer_kernel(
    ushort* __restrict__ Eio,
    const ushort* __restrict__ HA, const ushort* __restrict__ HB,
    const int* __restrict__ SRC, const int* __restrict__ DST,
    const ushort* __restrict__ W1t, const ushort* __restrict__ B1,
    const ushort* __restrict__ W2t, const ushort* __restrict__ B2,
    int ntiles, int Etot)
{
    __shared__ __align__(16) ushort sW1[96 * WSTR], sW2[96 * WSTR];
    __shared__ float sb1[96], sb2[96];
    int t = threadIdx.x;
    stageW<512>(sW1, W1t, t);
    stageW<512>(sW2, W2t, t);
    if (t < 96) { sb1[t] = bf2f(B1[t]); sb2[t] = bf2f(B2[t]); }
    __syncthreads();
    const int wave = t >> 6, lane = t & 63, lr = lane & 15, cg = lane >> 4, lk = cg * 8;
    const int srcA = ((cg & 1) * 2) * 16 + lr;   // sister lanes holding our k-slices
    const int srcB = srcA + 16;
    const bool hi = (cg >> 1) != 0;

    for (int tile = blockIdx.x; tile < ntiles; tile += gridDim.x) {
        int rbase = tile * 128 + wave * 16;
        int ra = rbase + lr; if (ra > Etot - 1) ra = Etot - 1;
        const ushort* arow = Eio + (size_t)ra * 96 + lk;
        short8 a0 = ld8(arow), a1 = ld8(arow + 32), a2 = ld8(arow + 64);

        // GEMM1 swapped: lane gets g_pre[row ra][n*16 + cg*4 + j]
        f32x4 accT[6];
#pragma unroll
        for (int n = 0; n < 6; n++) {
            f32x4 z = {0.f, 0.f, 0.f, 0.f}; accT[n] = z;
            const ushort* wb = sW1 + (n * 16 + lr) * WSTR + lk;
            accT[n] = MFMA(ld8(wb), a0, accT[n]);
            accT[n] = MFMA(ld8(wb + 32), a1, accT[n]);
            accT[n] = MFMA(ld8(wb + 64), a2, accT[n]);
        }

        // epilogue on own row: gathers (8B vector), bias, GELU, pack bf16 pairs
        int s0 = SRC[ra], d0 = DST[ra];
        const ushort* pa = HA + (size_t)s0 * 96 + cg * 4;
        const ushort* pb = HB + (size_t)d0 * 96 + cg * 4;
        uint pk[12];
#pragma unroll
        for (int n = 0; n < 6; n++) {
            uint2 ua = *(const uint2*)(pa + n * 16);
            uint2 ub = *(const uint2*)(pb + n * 16);
            const float* b1p = sb1 + n * 16 + cg * 4;
            float g0f = gelu_f(accT[n][0] + bf2f((ushort)ua.x) + bf2f((ushort)ub.x) + b1p[0]);
            float g1f = gelu_f(accT[n][1] + bf2f((ushort)(ua.x >> 16)) + bf2f((ushort)(ub.x >> 16)) + b1p[1]);
            float g2f = gelu_f(accT[n][2] + bf2f((ushort)ua.y) + bf2f((ushort)ub.y) + b1p[2]);
            float g3f = gelu_f(accT[n][3] + bf2f((ushort)(ua.y >> 16)) + bf2f((ushort)(ub.y >> 16)) + b1p[3]);
            pk[2 * n]     = (uint)f2bf(g0f) | ((uint)f2bf(g1f) << 16);
            pk[2 * n + 1] = (uint)f2bf(g2f) | ((uint)f2bf(g3f) << 16);
        }

        // shuffle-reassemble GEMM2 A-fragments
        short8 frag[3];
#pragma unroll
        for (int m = 0; m < 3; m++) {
            int nlo = 2 * m, nhi = 2 * m + 1;
            uint alo0 = (uint)__shfl((int)pk[2 * nlo],     srcA, 64);
            uint alo1 = (uint)__shfl((int)pk[2 * nlo + 1], srcA, 64);
            uint ahi0 = (uint)__shfl((int)pk[2 * nhi],     srcA, 64);
            uint ahi1 = (uint)__shfl((int)pk[2 * nhi + 1], srcA, 64);
            uint blo0 = (uint)__shfl((int)pk[2 * nlo],     srcB, 64);
            uint blo1 = (uint)__shfl((int)pk[2 * nlo + 1], srcB, 64);
            uint bhi0 = (uint)__shfl((int)pk[2 * nhi],     srcB, 64);
            uint bhi1 = (uint)__shfl((int)pk[2 * nhi + 1], srcB, 64);
            uint d0w = hi ? ahi0 : alo0;
            uint d1w = hi ? ahi1 : alo1;
            uint d2w = hi ? bhi0 : blo0;
            uint d3w = hi ? bhi1 : blo1;
            frag[m][0] = (short)(d0w & 0xffff); frag[m][1] = (short)(d0w >> 16);
            frag[m][2] = (short)(d1w & 0xffff); frag[m][3] = (short)(d1w >> 16);
            frag[m][4] = (short)(d2w & 0xffff); frag[m][5] = (short)(d2w >> 16);
            frag[m][6] = (short)(d3w & 0xffff); frag[m][7] = (short)(d3w >> 16);
        }

        // GEMM2 standard: out rows = e-rows, cols = features
        f32x4 acc2[6];
#pragma unroll
        for (int n = 0; n < 6; n++) {
            f32x4 z = {0.f, 0.f, 0.f, 0.f}; acc2[n] = z;
            const ushort* wb = sW2 + (n * 16 + lr) * WSTR + lk;
            acc2[n] = MFMA(frag[0], ld8(wb), acc2[n]);
            acc2[n] = MFMA(frag[1], ld8(wb + 32), acc2[n]);
            acc2[n] = MFMA(frag[2], ld8(wb + 64), acc2[n]);
        }
#pragma unroll
        for (int j = 0; j < 4; j++) {
            int r = rbase + cg * 4 + j;
            if (r < Etot) {
                ushort* erow = Eio + (size_t)r * 96;
#pragma unroll
                for (int n = 0; n < 6; n++) {
                    int c = n * 16 + lr;
                    float v = acc2[n][j] + sb2[c] + bf2f(erow[c]);
                    erow[c] = f2bf(v);   // in-place e update (row owned by this wave)
                }
            }
        }
    }
}

// ---------------- fused node layer (CSR gather-sum of sorted e) ----------------
template <bool HF32>
__global__ __launch_bounds__(256) void node_layer_kernel(
    float* __restrict__ HF, ushort* __restrict__ HBF,
    const ushort* __restrict__ EB, const int* __restrict__ ROWPTR,
    const ushort* __restrict__ W1at, const ushort* __restrict__ W1bt,
    const ushort* __restrict__ B1, const ushort* __restrict__ W2t,
    const ushort* __restrict__ B2, int R)
{
    __shared__ __align__(16) ushort sWa[96 * WSTR], sWb[96 * WSTR], sW2[96 * WSTR];
    __shared__ __align__(16) ushort gscr[4][16 * WSTR];
    __shared__ float sb1[96], sb2[96];
    int t = threadIdx.x;
    stageW<256>(sWa, W1at, t);
    stageW<256>(sWb, W1bt, t);
    stageW<256>(sW2, W2t, t);
    if (t < 96) { sb1[t] = bf2f(B1[t]); sb2[t] = bf2f(B2[t]); }
    __syncthreads();
    const int wave = t >> 6, lane = t & 63, lr = lane & 15, cg = lane >> 4, lk = cg * 8;
    int rbase = blockIdx.x * 64 + wave * 16;
    int ra = rbase + lr; if (ra > R - 1) ra = R - 1;
    const ushort* hrow = HBF + (size_t)ra * 96 + lk;
    short8 a0 = ld8(hrow), a1 = ld8(hrow + 32), a2 = ld8(hrow + 64);

    float ag[24];
#pragma unroll
    for (int i = 0; i < 24; i++) ag[i] = 0.f;
    int beg = ROWPTR[ra], end = ROWPTR[ra + 1];
    for (int k = beg; k < end; k++) {
        const ushort* er = EB + (size_t)k * 96 + lk;
        short8 e0 = ld8(er), e1 = ld8(er + 32), e2 = ld8(er + 64);
#pragma unroll
        for (int i = 0; i < 8; i++) {
            ag[i]      += bf2f((ushort)e0[i]);
            ag[8 + i]  += bf2f((ushort)e1[i]);
            ag[16 + i] += bf2f((ushort)e2[i]);
        }
    }
    short8 g0, g1, g2;
#pragma unroll
    for (int i = 0; i < 8; i++) {
        g0[i] = (short)f2bf(ag[i]);
        g1[i] = (short)f2bf(ag[8 + i]);
        g2[i] = (short)f2bf(ag[16 + i]);
    }

    f32x4 acc[6];
#pragma unroll
    for (int n = 0; n < 6; n++) {
        f32x4 z = {0.f, 0.f, 0.f, 0.f}; acc[n] = z;
        const ushort* wa = sWa + (n * 16 + lr) * WSTR + lk;
        const ushort* wb = sWb + (n * 16 + lr) * WSTR + lk;
        acc[n] = MFMA(a0, ld8(wa), acc[n]);
        acc[n] = MFMA(a1, ld8(wa + 32), acc[n]);
        acc[n] = MFMA(a2, ld8(wa + 64), acc[n]);
        acc[n] = MFMA(g0, ld8(wb), acc[n]);
        acc[n] = MFMA(g1, ld8(wb + 32), acc[n]);
        acc[n] = MFMA(g2, ld8(wb + 64), acc[n]);
    }
    ushort* g = gscr[wave];
#pragma unroll
    for (int j = 0; j < 4; j++) {
        int rl = cg * 4 + j;
#pragma unroll
        for (int n = 0; n < 6; n++) {
            int c = n * 16 + lr;
            g[rl * WSTR + c] = f2bf(gelu_f(acc[n][j] + sb1[c]));
        }
    }
    __syncthreads();
    const ushort* grow = g + lr * WSTR + lk;
    short8 b0 = ld8(grow), b1v = ld8(grow + 32), b2v = ld8(grow + 64);
    f32x4 acc2[6];
#pragma unroll
    for (int n = 0; n < 6; n++) {
        f32x4 z = {0.f, 0.f, 0.f, 0.f}; acc2[n] = z;
        const ushort* wb = sW2 + (n * 16 + lr) * WSTR + lk;
        acc2[n] = MFMA(b0, ld8(wb), acc2[n]);
        acc2[n] = MFMA(b1v, ld8(wb + 32), acc2[n]);
        acc2[n] = MFMA(b2v, ld8(wb + 64), acc2[n]);
    }
#pragma unroll
    for (int j = 0; j < 4; j++) {
        int r = rbase + cg * 4 + j;
        if (r < R) {
#pragma unroll
            for (int n = 0; n < 6; n++) {
                int c = n * 16 + lr;
                size_t idx = (size_t)r * 96 + c;
                float base;
                if constexpr (HF32) base = HF[idx]; else base = bf2f(HBF[idx]);
                float v = base + acc2[n][j] + sb2[c];
                if constexpr (HF32) HF[idx] = v;
                HBF[idx] = f2bf(v);
            }
        }
    }
}

// ---- head (fp32 out): swapped GEMM, row-local epilogue, 2-shuffle reduce ----
template <bool GATHER>
__global__ __launch_bounds__(256) void head_kernel(
    const ushort* __restrict__ Arows,
    const ushort* __restrict__ HA, const ushort* __restrict__ HB,
    const int* __restrict__ SRC, const int* __restrict__ DST,
    const ushort* __restrict__ W1t, const ushort* __restrict__ B1,
    const ushort* __restrict__ W2v, const ushort* __restrict__ B2,
    float* __restrict__ Out, const int* __restrict__ EID, int R)
{
    __shared__ __align__(16) ushort sW1[96 * WSTR];
    __shared__ float sb1[96], sw2[96];
    __shared__ float sb2s;
    int t = threadIdx.x;
    stageW<256>(sW1, W1t, t);
    if (t < 96) { sb1[t] = bf2f(B1[t]); sw2[t] = bf2f(W2v[t]); }
    if (t == 0) sb2s = bf2f(B2[0]);
    __syncthreads();
    const int wave = t >> 6, lane = t & 63, lr = lane & 15, cg = lane >> 4, lk = cg * 8;
    int rbase = blockIdx.x * 64 + wave * 16;
    int ra = rbase + lr; if (ra > R - 1) ra = R - 1;
    const ushort* arow = Arows + (size_t)ra * 96 + lk;
    short8 a0 = ld8(arow), a1 = ld8(arow + 32), a2 = ld8(arow + 64);

    // swapped GEMM: accT[n][j] = (A@W1)[row ra][col n*16+cg*4+j]
    f32x4 accT[6];
#pragma unroll
    for (int n = 0; n < 6; n++) {
        f32x4 z = {0.f, 0.f, 0.f, 0.f}; accT[n] = z;
        const ushort* wb = sW1 + (n * 16 + lr) * WSTR + lk;
        accT[n] = MFMA(ld8(wb), a0, accT[n]);
        accT[n] = MFMA(ld8(wb + 32), a1, accT[n]);
        accT[n] = MFMA(ld8(wb + 64), a2, accT[n]);
    }

    const ushort* pa = nullptr; const ushort* pb = nullptr;
    if constexpr (GATHER) {
        pa = HA + (size_t)SRC[ra] * 96 + cg * 4;
        pb = HB + (size_t)DST[ra] * 96 + cg * 4;
    }
    float s = 0.f;
#pragma unroll
    for (int n = 0; n < 6; n++) {
        const float* b1p = sb1 + n * 16 + cg * 4;
        const float* w2p = sw2 + n * 16 + cg * 4;
        float v0 = accT[n][0] + b1p[0];
        float v1 = accT[n][1] + b1p[1];
        float v2 = accT[n][2] + b1p[2];
        float v3 = accT[n][3] + b1p[3];
        if constexpr (GATHER) {
            uint2 ua = *(const uint2*)(pa + n * 16);
            uint2 ub = *(const uint2*)(pb + n * 16);
            v0 += bf2f((ushort)ua.x) + bf2f((ushort)ub.x);
            v1 += bf2f((ushort)(ua.x >> 16)) + bf2f((ushort)(ub.x >> 16));
            v2 += bf2f((ushort)ua.y) + bf2f((ushort)ub.y);
            v3 += bf2f((ushort)(ua.y >> 16)) + bf2f((ushort)(ub.y >> 16));
        }
        s += gelu_f(v0) * w2p[0] + gelu_f(v1) * w2p[1]
           + gelu_f(v2) * w2p[2] + gelu_f(v3) * w2p[3];
    }
    s += __shfl_xor(s, 16, 64);
    s += __shfl_xor(s, 32, 64);
    int r = rbase + lr;
    if (cg == 0 && r < R) {
        int ro = EID ? EID[r] : r;
        Out[ro] = s + sb2s;   // FP32 store (scatter to original order)
    }
}

// ---------------------------------- host ----------------------------------
extern "C" void kernel_launch(void* const* d_in, const int* in_sizes, int n_in,
                              void* d_out, int out_size, void* d_ws, size_t ws_size,
                              hipStream_t stream)
{
    (void)n_in; (void)out_size;
    const int N = in_sizes[0] / 6;
    const int E = in_sizes[2] / 8;

    auto a256 = [](size_t b) { return (b + 255) & ~(size_t)255; };
    const size_t sz_flags = 256;
    const size_t sz_wt    = a256((size_t)34 * 9216 * 2);
    const size_t sz_sm    = a256(3650 * 2);
    const size_t sz_hbf   = a256((size_t)N * 96 * 2);
    const size_t sz_ebuf  = a256((size_t)E * 96 * 2);
    const size_t sz_idx   = a256((size_t)E * 4);
    const size_t sz_np    = a256((size_t)(N + 1) * 4);
    const size_t sz_xbf   = a256((size_t)N * 6 * 2);
    const size_t sz_eabf  = a256((size_t)E * 8 * 2);
    const size_t sz_hf    = a256((size_t)N * 96 * 4);

    const size_t need_base   = sz_flags + sz_wt + sz_sm + 3 * sz_hbf + sz_ebuf
                             + 2 * sz_np + 3 * sz_idx;
    const size_t need_copies = need_base + 2 * sz_idx + sz_xbf + sz_eabf;
    const size_t need_full   = need_copies + sz_hf;
    int mode = (ws_size >= need_full) ? 0 : (ws_size >= need_copies) ? 1 : 2;
    const bool hf32 = (mode == 0), copies = (mode <= 1);

    char* ws = (char*)d_ws;
    size_t off = 0;
    auto alloc = [&](size_t bytes) -> void* { void* p = ws + off; off += bytes; return p; };
    int*    flags  = (int*)alloc(sz_flags);
    ushort* wtpool = (ushort*)alloc(sz_wt);
    ushort* smalls = (ushort*)alloc(sz_sm);
    ushort* h_bf   = (ushort*)alloc(sz_hbf);
    ushort* hA     = (ushort*)alloc(sz_hbf);
    ushort* hB     = (ushort*)alloc(sz_hbf);
    ushort* ebuf   = (ushort*)alloc(sz_ebuf);
    int*    cnt    = (int*)alloc(sz_np);
    int*    rowptr = (int*)alloc(sz_np);
    int*    src_s  = (int*)alloc(sz_idx);
    int*    dst_s  = (int*)alloc(sz_idx);
    int*    eid    = (int*)alloc(sz_idx);
    const int* eidx = (const int*)d_in[1];
    int*    src32 = copies ? (int*)alloc(sz_idx) : (int*)eidx;
    int*    dst32 = copies ? (int*)alloc(sz_idx) : (int*)(eidx + E);
    ushort* x_bf  = copies ? (ushort*)alloc(sz_xbf)  : (ushort*)d_in[0];
    ushort* ea_bf = copies ? (ushort*)alloc(sz_eabf) : (ushort*)d_in[2];
    float*  h_f32 = hf32 ? (float*)alloc(sz_hf) : nullptr;

    SPk sp;
    const int soff[17] = {0, 576, 672, 768, 1536, 1632, 1728, 2112, 2496, 2880,
                          3264, 3360, 3456, 3552, 3648, 3649, 3650};
    for (int i = 0; i < 17; i++) sp.off[i] = soff[i];
    sp.src[0]  = d_in[3];   sp.src[1]  = d_in[4];   sp.src[2]  = d_in[6];
    sp.src[3]  = d_in[7];   sp.src[4]  = d_in[8];   sp.src[5]  = d_in[10];
    sp.src[6]  = d_in[12];  sp.src[7]  = d_in[14];  sp.src[8]  = d_in[16];
    sp.src[9]  = d_in[18];  sp.src[10] = d_in[20];  sp.src[11] = d_in[21];
    sp.src[12] = d_in[24];  sp.src[13] = d_in[25];  sp.src[14] = d_in[22];
    sp.src[15] = d_in[26];
    auto SM = [&](int o) { return smalls + o; };

    TPk tp; int q = 0;
    tp.base[q] = d_in[5];  tp.eloff[q++] = 0;
    tp.base[q] = d_in[9];  tp.eloff[q++] = 0;
    for (int l = 0; l < 4; l++) {
        tp.base[q] = d_in[11]; tp.eloff[q++] = l * 27648;
        tp.base[q] = d_in[11]; tp.eloff[q++] = l * 27648 + 9216;
        tp.base[q] = d_in[11]; tp.eloff[q++] = l * 27648 + 18432;
        tp.base[q] = d_in[13]; tp.eloff[q++] = l * 9216;
        tp.base[q] = d_in[15]; tp.eloff[q++] = l * 18432;
        tp.base[q] = d_in[15]; tp.eloff[q++] = l * 18432 + 9216;
        tp.base[q] = d_in[17]; tp.eloff[q++] = l * 9216;
    }
    tp.base[q] = d_in[23]; tp.eloff[q++] = 0;
    tp.base[q] = d_in[23]; tp.eloff[q++] = 9216;
    tp.base[q] = d_in[23]; tp.eloff[q++] = 18432;
    tp.base[q] = d_in[19]; tp.eloff[q++] = 0;
    auto WT = [&](int i) { return wtpool + (size_t)i * 9216; };

    const int nblkN = (N + 63) / 64;
    const int nblkE = (E + 63) / 64;
    const int ntilE128 = (E + 127) / 128;

    // ---- prep ----
    detect_kernel<<<1, 256, 0, stream>>>((const ushort*)d_in[0], (const uint*)d_in[1], flags);
    smalls_kernel<<<1, 256, 0, stream>>>(sp, smalls, flags);
    transpose_k<<<34, 256, 0, stream>>>(tp, wtpool, flags);
    if (copies) {
        idx_convert<<<1024, 256, 0, stream>>>(eidx, src32, dst32, flags, E);
        xe_convert<<<2048, 256, 0, stream>>>(d_in[0], d_in[2], x_bf, ea_bf, flags,
                                             (size_t)N * 6, (size_t)E * 8);
    }
    hipMemsetAsync(cnt, 0, (size_t)(N + 1) * 4, stream);
    hist_kernel<<<1024, 256, 0, stream>>>(dst32, cnt, E);
    prefix_kernel<<<1, 1024, 0, stream>>>(cnt, rowptr, N, E);
    scatter_kernel<<<1024, 256, 0, stream>>>(src32, dst32, cnt, src_s, dst_s, eid, E);

    // ---- encoders (edge encoder writes e in dst-sorted order) ----
    if (hf32)
        encoder_kernel<6, true><<<nblkN, 256, 0, stream>>>(x_bf, SM(0), SM(576), WT(0), SM(672), h_bf, h_f32, nullptr, N);
    else
        encoder_kernel<6, false><<<nblkN, 256, 0, stream>>>(x_bf, SM(0), SM(576), WT(0), SM(672), h_bf, nullptr, nullptr, N);
    encoder_kernel<8, false><<<nblkE, 256, 0, stream>>>(ea_bf, SM(768), SM(1536), WT(1), SM(1632), ebuf, nullptr, eid, E);

    // ---- message-passing layers ----
    for (int l = 0; l < 4; l++) {
        int b = 2 + l * 7;
        gemm_dual_kernel<<<nblkN, 256, 0, stream>>>(h_bf, WT(b + 0), WT(b + 1), hA, hB, N);
        int egrid = ntilE128 < 2048 ? ntilE128 : 2048;
        edge_layer_kernel<<<egrid, 512, 0, stream>>>(
            ebuf, hA, hB, src_s, dst_s, WT(b + 2), SM(1728 + l * 96),
            WT(b + 3), SM(2112 + l * 96), ntilE128, E);
        if (hf32)
            node_layer_kernel<true><<<nblkN, 256, 0, stream>>>(
                h_f32, h_bf, ebuf, rowptr, WT(b + 4), WT(b + 5), SM(2496 + l * 96),
                WT(b + 6), SM(2880 + l * 96), N);
        else
            node_layer_kernel<false><<<nblkN, 256, 0, stream>>>(
                nullptr, h_bf, ebuf, rowptr, WT(b + 4), WT(b + 5), SM(2496 + l * 96),
                WT(b + 6), SM(2880 + l * 96), N);
    }

    // ---- heads (FP32 output; edge head scatters to original edge order) ----
    gemm_dual_kernel<<<nblkN, 256, 0, stream>>>(h_bf, WT(30), WT(31), hA, hB, N);
    float* out = (float*)d_out;
    head_kernel<true><<<nblkE, 256, 0, stream>>>(
        ebuf, hA, hB, src_s, dst_s, WT(32), SM(3456), SM(3552), SM(3649), out, eid, E);
    head_kernel<false><<<nblkN, 256, 0, stream>>>(
        h_bf, nullptr, nullptr, nullptr, nullptr, WT(33), SM(3264), SM(3360), SM(3648), out + E, nullptr, N);
}

// Round 15
// 1461.430 us; speedup vs baseline: 2.9480x; 2.9480x over previous
//
#include <hip/hip_runtime.h>
#include <hip/hip_bf16.h>
#include <math.h>

// CaloClusterNet: 4-layer edge/node MPNN, H=96, bf16 compute, fp32 accumulate.
// Round 15: REVERT edge_layer to R12's proven 183us version (LDS transpose,
// 512 thr, VGPR 52 — R14's launch_bounds(512,6) forced VGPR=40 and spilled
// 2.6GB/dispatch scratch traffic, 870us). KEEP R14's swapped-GEMM head_kernel
// (strictly less work: 8B vector gathers + 2-shuffle reduce).

typedef __attribute__((ext_vector_type(8))) short short8;
typedef __attribute__((ext_vector_type(4))) float f32x4;

#define MFMA(a, b, c) __builtin_amdgcn_mfma_f32_16x16x32_bf16((a), (b), (c), 0, 0, 0)
#define WSTR 112  // LDS row stride in ushorts (224B, 16B-aligned)

__device__ __forceinline__ float bf2f(ushort u) {
    union { uint i; float f; } v; v.i = ((uint)u) << 16; return v.f;
}
__device__ __forceinline__ ushort f2bf(float f) {
    union { float f; uint i; } v; v.f = f;
    uint b = v.i;
    return (ushort)((b + 0x7FFFu + ((b >> 16) & 1u)) >> 16);  // RNE
}
__device__ __forceinline__ float gelu_f(float x) {
    return 0.5f * x * (1.0f + erff(x * 0.70710678118654752440f));
}
__device__ __forceinline__ short8 ld8(const ushort* p) { return *(const short8*)p; }
__device__ __forceinline__ ushort cvt_elem(const void* p, size_t j, int f32) {
    return f32 ? f2bf(((const float*)p)[j]) : ((const ushort*)p)[j];
}
template <int NT>
__device__ __forceinline__ void stageW(ushort* dst, const ushort* src, int t) {
    for (int i = t; i < 1152; i += NT) {
        int row = i / 12, ch = i - row * 12;
        ((short8*)dst)[row * 14 + ch] = ((const short8*)src)[i];
    }
}

// ---------------- dtype detector ----------------
__global__ __launch_bounds__(256) void detect_kernel(
    const ushort* __restrict__ X, const uint* __restrict__ IDX, int* __restrict__ flags)
{
    __shared__ int cnt[2];
    if (threadIdx.x == 0) { cnt[0] = 0; cnt[1] = 0; }
    __syncthreads();
    int plaus = 0;
    for (int i = threadIdx.x; i < 2048; i += 256) {
        float v = fabsf(bf2f(X[i]));
        if (v > 1e-3f && v < 100.f) plaus++;
    }
    atomicAdd(&cnt[0], plaus);
    int nz = 0;
    for (int i = threadIdx.x; i < 1024; i += 256)
        if (IDX[2 * i + 1] != 0) nz++;
    atomicAdd(&cnt[1], nz);
    __syncthreads();
    if (threadIdx.x == 0) {
        flags[0] = (cnt[0] < 1843) ? 1 : 0;  // fp32 if <90% plausible as bf16
        flags[1] = (cnt[1] == 0) ? 1 : 0;    // int64 if all high words zero
    }
}

// ---------------- small arrays -> bf16 ----------------
struct SPk { const void* src[16]; int off[17]; };
__global__ __launch_bounds__(256) void smalls_kernel(SPk p, ushort* __restrict__ dst,
                                                     const int* __restrict__ flags) {
    int f = flags[0];
    for (int i = threadIdx.x; i < 3650; i += 256) {
        int e = 0;
        while (e < 15 && i >= p.off[e + 1]) e++;
        dst[i] = cvt_elem(p.src[e], (size_t)(i - p.off[e]), f);
    }
}

// ---------------- weight transpose: 34 96x96 matrices -> bf16 ----------------
struct TPk { const void* base[34]; int eloff[34]; };
__global__ __launch_bounds__(256) void transpose_k(TPk p, ushort* __restrict__ dst,
                                                   const int* __restrict__ flags) {
    int f = flags[0];
    int m = blockIdx.x;
    const void* s = p.base[m];
    size_t off = (size_t)p.eloff[m];
    ushort* d = dst + (size_t)m * 9216;
    for (int i = threadIdx.x; i < 9216; i += 256) {
        int n = i / 96, k = i - n * 96;      // d[n*96+k] = s[k*96+n]
        d[i] = cvt_elem(s, off + (size_t)k * 96 + n, f);
    }
}

// ---------------- index canonicalization -> int32 ----------------
__global__ __launch_bounds__(256) void idx_convert(
    const int* __restrict__ eidx, int* __restrict__ s32, int* __restrict__ d32,
    const int* __restrict__ flags, int E)
{
    int f = flags[1];
    for (size_t i = (size_t)blockIdx.x * 256 + threadIdx.x; i < (size_t)E;
         i += (size_t)gridDim.x * 256) {
        s32[i] = f ? eidx[2 * i] : eidx[i];
        d32[i] = f ? eidx[2 * ((size_t)E + i)] : eidx[(size_t)E + i];
    }
}

// ---------------- x / edge_attr canonicalization -> bf16 ----------------
__global__ __launch_bounds__(256) void xe_convert(
    const void* __restrict__ xin, const void* __restrict__ ein,
    ushort* __restrict__ xb, ushort* __restrict__ eb,
    const int* __restrict__ flags, size_t nx, size_t ne)
{
    int f = flags[0];
    size_t total = nx + ne;
    for (size_t i = (size_t)blockIdx.x * 256 + threadIdx.x; i < total;
         i += (size_t)gridDim.x * 256) {
        if (i < nx) xb[i] = cvt_elem(xin, i, f);
        else        eb[i - nx] = cvt_elem(ein, i - nx, f);
    }
}

// ---------------- counting sort by dst: hist -> prefix -> scatter ----------------
__global__ __launch_bounds__(256) void hist_kernel(const int* __restrict__ d32,
                                                   int* __restrict__ cnt, int E) {
    for (size_t i = (size_t)blockIdx.x * 256 + threadIdx.x; i < (size_t)E;
         i += (size_t)gridDim.x * 256)
        atomicAdd(&cnt[d32[i]], 1);
}

__global__ __launch_bounds__(1024) void prefix_kernel(int* __restrict__ cnt,
                                                      int* __restrict__ rowptr,
                                                      int N, int E) {
    __shared__ int part[1024];
    int t = threadIdx.x;
    int chunk = (N + 1023) / 1024;
    int b = t * chunk, e = b + chunk; if (e > N) e = N;
    int s = 0;
    for (int i = b; i < e; i++) s += cnt[i];
    part[t] = s;
    __syncthreads();
    for (int off = 1; off < 1024; off <<= 1) {
        int v = (t >= off) ? part[t - off] : 0;
        __syncthreads();
        part[t] += v;
        __syncthreads();
    }
    int run = part[t] - s;  // exclusive prefix
    for (int i = b; i < e; i++) {
        int c = cnt[i];
        rowptr[i] = run;
        cnt[i] = run;       // reuse cnt as scatter cursor
        run += c;
    }
    if (t == 1023) rowptr[N] = E;
}

__global__ __launch_bounds__(256) void scatter_kernel(
    const int* __restrict__ s32, const int* __restrict__ d32,
    int* __restrict__ cursor, int* __restrict__ ss, int* __restrict__ ds,
    int* __restrict__ eid, int E)
{
    for (size_t i = (size_t)blockIdx.x * 256 + threadIdx.x; i < (size_t)E;
         i += (size_t)gridDim.x * 256) {
        int d = d32[i];
        int pos = atomicAdd(&cursor[d], 1);
        ss[pos] = s32[i];
        ds[pos] = d;
        eid[pos] = (int)i;
    }
}

// ---------------- encoder (optional row-gather via EID for sorted e) ----------------
template <int K, bool WF32>
__global__ __launch_bounds__(256) void encoder_kernel(
    const ushort* __restrict__ X, const ushort* __restrict__ W1,
    const ushort* __restrict__ B1, const ushort* __restrict__ W2t,
    const ushort* __restrict__ B2, ushort* __restrict__ OutB,
    float* __restrict__ OutF, const int* __restrict__ EID, int R)
{
    __shared__ __align__(16) ushort sW2[96 * WSTR];
    __shared__ float sW1[K * 96];
    __shared__ float sb1[96], sb2[96];
    __shared__ __align__(16) ushort gscr[4][16 * WSTR];
    int t = threadIdx.x;
    stageW<256>(sW2, W2t, t);
    for (int i = t; i < K * 96; i += 256) sW1[i] = bf2f(W1[i]);
    if (t < 96) { sb1[t] = bf2f(B1[t]); sb2[t] = bf2f(B2[t]); }
    __syncthreads();

    const int wave = t >> 6, lane = t & 63, lr = lane & 15, cg = lane >> 4, lk = cg * 8;
    int rbase = blockIdx.x * 64 + wave * 16;

    float wf[K][6];
#pragma unroll
    for (int k = 0; k < K; k++)
#pragma unroll
        for (int n = 0; n < 6; n++) wf[k][n] = sW1[k * 96 + n * 16 + lr];

    ushort* g = gscr[wave];
#pragma unroll
    for (int j = 0; j < 4; j++) {
        int r = rbase + cg * 4 + j;
        int rc = r < R ? r : R - 1;
        int rx = EID ? EID[rc] : rc;
        float xr[K];
        const uint* xu = (const uint*)(X + (size_t)rx * K);
#pragma unroll
        for (int q = 0; q < K / 2; q++) {
            uint u = xu[q];
            xr[2 * q] = bf2f((ushort)u); xr[2 * q + 1] = bf2f((ushort)(u >> 16));
        }
#pragma unroll
        for (int n = 0; n < 6; n++) {
            float v = sb1[n * 16 + lr];
#pragma unroll
            for (int k = 0; k < K; k++) v += xr[k] * wf[k][n];
            g[(cg * 4 + j) * WSTR + n * 16 + lr] = f2bf(gelu_f(v));
        }
    }
    __syncthreads();

    const ushort* grow = g + lr * WSTR + lk;
    short8 a0 = ld8(grow), a1 = ld8(grow + 32), a2 = ld8(grow + 64);
    f32x4 acc[6];
#pragma unroll
    for (int n = 0; n < 6; n++) {
        f32x4 z = {0.f, 0.f, 0.f, 0.f}; acc[n] = z;
        const ushort* wb = sW2 + (n * 16 + lr) * WSTR + lk;
        acc[n] = MFMA(a0, ld8(wb), acc[n]);
        acc[n] = MFMA(a1, ld8(wb + 32), acc[n]);
        acc[n] = MFMA(a2, ld8(wb + 64), acc[n]);
    }
#pragma unroll
    for (int j = 0; j < 4; j++) {
        int r = rbase + cg * 4 + j;
        if (r < R) {
#pragma unroll
            for (int n = 0; n < 6; n++) {
                int c = n * 16 + lr;
                float v = acc[n][j] + sb2[c];
                OutB[(size_t)r * 96 + c] = f2bf(v);
                if constexpr (WF32) OutF[(size_t)r * 96 + c] = v;
            }
        }
    }
}

// ---------------- dual GEMM ----------------
__global__ __launch_bounds__(256) void gemm_dual_kernel(
    const ushort* __restrict__ A, const ushort* __restrict__ W1t,
    const ushort* __restrict__ W2t, ushort* __restrict__ O1,
    ushort* __restrict__ O2, int R)
{
    __shared__ __align__(16) ushort sW1[96 * WSTR], sW2[96 * WSTR];
    int t = threadIdx.x;
    stageW<256>(sW1, W1t, t);
    stageW<256>(sW2, W2t, t);
    __syncthreads();
    const int wave = t >> 6, lane = t & 63, lr = lane & 15, cg = lane >> 4, lk = cg * 8;
    int rbase = blockIdx.x * 64 + wave * 16;
    int ra = rbase + lr; if (ra > R - 1) ra = R - 1;
    const ushort* arow = A + (size_t)ra * 96 + lk;
    short8 a0 = ld8(arow), a1 = ld8(arow + 32), a2 = ld8(arow + 64);
    f32x4 acc1[6], acc2[6];
#pragma unroll
    for (int n = 0; n < 6; n++) {
        f32x4 z = {0.f, 0.f, 0.f, 0.f}; acc1[n] = z; acc2[n] = z;
        const ushort* w1 = sW1 + (n * 16 + lr) * WSTR + lk;
        const ushort* w2 = sW2 + (n * 16 + lr) * WSTR + lk;
        acc1[n] = MFMA(a0, ld8(w1), acc1[n]);
        acc1[n] = MFMA(a1, ld8(w1 + 32), acc1[n]);
        acc1[n] = MFMA(a2, ld8(w1 + 64), acc1[n]);
        acc2[n] = MFMA(a0, ld8(w2), acc2[n]);
        acc2[n] = MFMA(a1, ld8(w2 + 32), acc2[n]);
        acc2[n] = MFMA(a2, ld8(w2 + 64), acc2[n]);
    }
#pragma unroll
    for (int j = 0; j < 4; j++) {
        int r = rbase + cg * 4 + j;
        if (r < R) {
#pragma unroll
            for (int n = 0; n < 6; n++) {
                int c = n * 16 + lr;
                O1[(size_t)r * 96 + c] = f2bf(acc1[n][j]);
                O2[(size_t)r * 96 + c] = f2bf(acc2[n][j]);
            }
        }
    }
}

// ---------------- fused edge layer (R12 version: sorted rows, no atomics) ----------------
__global__ __launch_bounds__(512) void edge_layer_kernel(
    ushort* __restrict__ Eio,
    const ushort* __restrict__ HA, const ushort* __restrict__ HB,
    const int* __restrict__ SRC, const int* __restrict__ DST,
    const ushort* __restrict__ W1t, const ushort* __restrict__ B1,
    const ushort* __restrict__ W2t, const ushort* __restrict__ B2,
    int ntiles, int Etot)
{
    __shared__ __align__(16) ushort sW1[96 * WSTR], sW2[96 * WSTR];
    __shared__ __align__(16) ushort gscr[8][16 * WSTR];
    __shared__ float sb1[96], sb2[96];
    int t = threadIdx.x;
    stageW<512>(sW1, W1t, t);
    stageW<512>(sW2, W2t, t);
    if (t < 96) { sb1[t] = bf2f(B1[t]); sb2[t] = bf2f(B2[t]); }
    __syncthreads();
    const int wave = t >> 6, lane = t & 63, lr = lane & 15, cg = lane >> 4, lk = cg * 8;
    ushort* g = gscr[wave];

    for (int tile = blockIdx.x; tile < ntiles; tile += gridDim.x) {
        int rbase = tile * 128 + wave * 16;
        int ra = rbase + lr; if (ra > Etot - 1) ra = Etot - 1;
        const ushort* arow = Eio + (size_t)ra * 96 + lk;
        short8 a0 = ld8(arow), a1 = ld8(arow + 32), a2 = ld8(arow + 64);
        f32x4 acc[6];
#pragma unroll
        for (int n = 0; n < 6; n++) {
            f32x4 z = {0.f, 0.f, 0.f, 0.f}; acc[n] = z;
            const ushort* wb = sW1 + (n * 16 + lr) * WSTR + lk;
            acc[n] = MFMA(a0, ld8(wb), acc[n]);
            acc[n] = MFMA(a1, ld8(wb + 32), acc[n]);
            acc[n] = MFMA(a2, ld8(wb + 64), acc[n]);
        }
        int s4[4], d4[4];
#pragma unroll
        for (int j = 0; j < 4; j++) {
            int r = rbase + cg * 4 + j; if (r > Etot - 1) r = Etot - 1;
            s4[j] = SRC[r]; d4[j] = DST[r];
        }
#pragma unroll
        for (int j = 0; j < 4; j++) {
            const ushort* pa = HA + (size_t)s4[j] * 96;
            const ushort* pb = HB + (size_t)d4[j] * 96;
            int rl = cg * 4 + j;
#pragma unroll
            for (int n = 0; n < 6; n++) {
                int c = n * 16 + lr;
                float v = acc[n][j] + bf2f(pa[c]) + bf2f(pb[c]) + sb1[c];
                g[rl * WSTR + c] = f2bf(gelu_f(v));
            }
        }
        __syncthreads();
        const ushort* grow = g + lr * WSTR + lk;
        short8 b0 = ld8(grow), b1v = ld8(grow + 32), b2v = ld8(grow + 64);
        f32x4 acc2[6];
#pragma unroll
        for (int n = 0; n < 6; n++) {
            f32x4 z = {0.f, 0.f, 0.f, 0.f}; acc2[n] = z;
            const ushort* wb = sW2 + (n * 16 + lr) * WSTR + lk;
            acc2[n] = MFMA(b0, ld8(wb), acc2[n]);
            acc2[n] = MFMA(b1v, ld8(wb + 32), acc2[n]);
            acc2[n] = MFMA(b2v, ld8(wb + 64), acc2[n]);
        }
#pragma unroll
        for (int j = 0; j < 4; j++) {
            int r = rbase + cg * 4 + j;
            if (r < Etot) {
                ushort* erow = Eio + (size_t)r * 96;
#pragma unroll
                for (int n = 0; n < 6; n++) {
                    int c = n * 16 + lr;
                    float v = acc2[n][j] + sb2[c] + bf2f(erow[c]);
                    erow[c] = f2bf(v);   // in-place e update (row owned here)
                }
            }
        }
        __syncthreads();
    }
}

// ---------------- fused node layer (CSR gather-sum of sorted e) ----------------
template <bool HF32>
__global__ __launch_bounds__(256) void node_layer_kernel(
    float* __restrict__ HF, ushort* __restrict__ HBF,
    const ushort* __restrict__ EB, const int* __restrict__ ROWPTR,
    const ushort* __restrict__ W1at, const ushort* __restrict__ W1bt,
    const ushort* __restrict__ B1, const ushort* __restrict__ W2t,
    const ushort* __restrict__ B2, int R)
{
    __shared__ __align__(16) ushort sWa[96 * WSTR], sWb[96 * WSTR], sW2[96 * WSTR];
    __shared__ __align__(16) ushort gscr[4][16 * WSTR];
    __shared__ float sb1[96], sb2[96];
    int t = threadIdx.x;
    stageW<256>(sWa, W1at, t);
    stageW<256>(sWb, W1bt, t);
    stageW<256>(sW2, W2t, t);
    if (t < 96) { sb1[t] = bf2f(B1[t]); sb2[t] = bf2f(B2[t]); }
    __syncthreads();
    const int wave = t >> 6, lane = t & 63, lr = lane & 15, cg = lane >> 4, lk = cg * 8;
    int rbase = blockIdx.x * 64 + wave * 16;
    int ra = rbase + lr; if (ra > R - 1) ra = R - 1;
    const ushort* hrow = HBF + (size_t)ra * 96 + lk;
    short8 a0 = ld8(hrow), a1 = ld8(hrow + 32), a2 = ld8(hrow + 64);

    float ag[24];
#pragma unroll
    for (int i = 0; i < 24; i++) ag[i] = 0.f;
    int beg = ROWPTR[ra], end = ROWPTR[ra + 1];
    for (int k = beg; k < end; k++) {
        const ushort* er = EB + (size_t)k * 96 + lk;
        short8 e0 = ld8(er), e1 = ld8(er + 32), e2 = ld8(er + 64);
#pragma unroll
        for (int i = 0; i < 8; i++) {
            ag[i]      += bf2f((ushort)e0[i]);
            ag[8 + i]  += bf2f((ushort)e1[i]);
            ag[16 + i] += bf2f((ushort)e2[i]);
        }
    }
    short8 g0, g1, g2;
#pragma unroll
    for (int i = 0; i < 8; i++) {
        g0[i] = (short)f2bf(ag[i]);
        g1[i] = (short)f2bf(ag[8 + i]);
        g2[i] = (short)f2bf(ag[16 + i]);
    }

    f32x4 acc[6];
#pragma unroll
    for (int n = 0; n < 6; n++) {
        f32x4 z = {0.f, 0.f, 0.f, 0.f}; acc[n] = z;
        const ushort* wa = sWa + (n * 16 + lr) * WSTR + lk;
        const ushort* wb = sWb + (n * 16 + lr) * WSTR + lk;
        acc[n] = MFMA(a0, ld8(wa), acc[n]);
        acc[n] = MFMA(a1, ld8(wa + 32), acc[n]);
        acc[n] = MFMA(a2, ld8(wa + 64), acc[n]);
        acc[n] = MFMA(g0, ld8(wb), acc[n]);
        acc[n] = MFMA(g1, ld8(wb + 32), acc[n]);
        acc[n] = MFMA(g2, ld8(wb + 64), acc[n]);
    }
    ushort* g = gscr[wave];
#pragma unroll
    for (int j = 0; j < 4; j++) {
        int rl = cg * 4 + j;
#pragma unroll
        for (int n = 0; n < 6; n++) {
            int c = n * 16 + lr;
            g[rl * WSTR + c] = f2bf(gelu_f(acc[n][j] + sb1[c]));
        }
    }
    __syncthreads();
    const ushort* grow = g + lr * WSTR + lk;
    short8 b0 = ld8(grow), b1v = ld8(grow + 32), b2v = ld8(grow + 64);
    f32x4 acc2[6];
#pragma unroll
    for (int n = 0; n < 6; n++) {
        f32x4 z = {0.f, 0.f, 0.f, 0.f}; acc2[n] = z;
        const ushort* wb = sW2 + (n * 16 + lr) * WSTR + lk;
        acc2[n] = MFMA(b0, ld8(wb), acc2[n]);
        acc2[n] = MFMA(b1v, ld8(wb + 32), acc2[n]);
        acc2[n] = MFMA(b2v, ld8(wb + 64), acc2[n]);
    }
#pragma unroll
    for (int j = 0; j < 4; j++) {
        int r = rbase + cg * 4 + j;
        if (r < R) {
#pragma unroll
            for (int n = 0; n < 6; n++) {
                int c = n * 16 + lr;
                size_t idx = (size_t)r * 96 + c;
                float base;
                if constexpr (HF32) base = HF[idx]; else base = bf2f(HBF[idx]);
                float v = base + acc2[n][j] + sb2[c];
                if constexpr (HF32) HF[idx] = v;
                HBF[idx] = f2bf(v);
            }
        }
    }
}

// ---- head (fp32 out): swapped GEMM, row-local epilogue, 2-shuffle reduce ----
template <bool GATHER>
__global__ __launch_bounds__(256) void head_kernel(
    const ushort* __restrict__ Arows,
    const ushort* __restrict__ HA, const ushort* __restrict__ HB,
    const int* __restrict__ SRC, const int* __restrict__ DST,
    const ushort* __restrict__ W1t, const ushort* __restrict__ B1,
    const ushort* __restrict__ W2v, const ushort* __restrict__ B2,
    float* __restrict__ Out, const int* __restrict__ EID, int R)
{
    __shared__ __align__(16) ushort sW1[96 * WSTR];
    __shared__ float sb1[96], sw2[96];
    __shared__ float sb2s;
    int t = threadIdx.x;
    stageW<256>(sW1, W1t, t);
    if (t < 96) { sb1[t] = bf2f(B1[t]); sw2[t] = bf2f(W2v[t]); }
    if (t == 0) sb2s = bf2f(B2[0]);
    __syncthreads();
    const int wave = t >> 6, lane = t & 63, lr = lane & 15, cg = lane >> 4, lk = cg * 8;
    int rbase = blockIdx.x * 64 + wave * 16;
    int ra = rbase + lr; if (ra > R - 1) ra = R - 1;
    const ushort* arow = Arows + (size_t)ra * 96 + lk;
    short8 a0 = ld8(arow), a1 = ld8(arow + 32), a2 = ld8(arow + 64);

    // swapped GEMM: accT[n][j] = (A@W1)[row ra][col n*16+cg*4+j]
    f32x4 accT[6];
#pragma unroll
    for (int n = 0; n < 6; n++) {
        f32x4 z = {0.f, 0.f, 0.f, 0.f}; accT[n] = z;
        const ushort* wb = sW1 + (n * 16 + lr) * WSTR + lk;
        accT[n] = MFMA(ld8(wb), a0, accT[n]);
        accT[n] = MFMA(ld8(wb + 32), a1, accT[n]);
        accT[n] = MFMA(ld8(wb + 64), a2, accT[n]);
    }

    const ushort* pa = nullptr; const ushort* pb = nullptr;
    if constexpr (GATHER) {
        pa = HA + (size_t)SRC[ra] * 96 + cg * 4;
        pb = HB + (size_t)DST[ra] * 96 + cg * 4;
    }
    float s = 0.f;
#pragma unroll
    for (int n = 0; n < 6; n++) {
        const float* b1p = sb1 + n * 16 + cg * 4;
        const float* w2p = sw2 + n * 16 + cg * 4;
        float v0 = accT[n][0] + b1p[0];
        float v1 = accT[n][1] + b1p[1];
        float v2 = accT[n][2] + b1p[2];
        float v3 = accT[n][3] + b1p[3];
        if constexpr (GATHER) {
            uint2 ua = *(const uint2*)(pa + n * 16);
            uint2 ub = *(const uint2*)(pb + n * 16);
            v0 += bf2f((ushort)ua.x) + bf2f((ushort)ub.x);
            v1 += bf2f((ushort)(ua.x >> 16)) + bf2f((ushort)(ub.x >> 16));
            v2 += bf2f((ushort)ua.y) + bf2f((ushort)ub.y);
            v3 += bf2f((ushort)(ua.y >> 16)) + bf2f((ushort)(ub.y >> 16));
        }
        s += gelu_f(v0) * w2p[0] + gelu_f(v1) * w2p[1]
           + gelu_f(v2) * w2p[2] + gelu_f(v3) * w2p[3];
    }
    s += __shfl_xor(s, 16, 64);
    s += __shfl_xor(s, 32, 64);
    int r = rbase + lr;
    if (cg == 0 && r < R) {
        int ro = EID ? EID[r] : r;
        Out[ro] = s + sb2s;   // FP32 store (scatter to original order)
    }
}

// ---------------------------------- host ----------------------------------
extern "C" void kernel_launch(void* const* d_in, const int* in_sizes, int n_in,
                              void* d_out, int out_size, void* d_ws, size_t ws_size,
                              hipStream_t stream)
{
    (void)n_in; (void)out_size;
    const int N = in_sizes[0] / 6;
    const int E = in_sizes[2] / 8;

    auto a256 = [](size_t b) { return (b + 255) & ~(size_t)255; };
    const size_t sz_flags = 256;
    const size_t sz_wt    = a256((size_t)34 * 9216 * 2);
    const size_t sz_sm    = a256(3650 * 2);
    const size_t sz_hbf   = a256((size_t)N * 96 * 2);
    const size_t sz_ebuf  = a256((size_t)E * 96 * 2);
    const size_t sz_idx   = a256((size_t)E * 4);
    const size_t sz_np    = a256((size_t)(N + 1) * 4);
    const size_t sz_xbf   = a256((size_t)N * 6 * 2);
    const size_t sz_eabf  = a256((size_t)E * 8 * 2);
    const size_t sz_hf    = a256((size_t)N * 96 * 4);

    const size_t need_base   = sz_flags + sz_wt + sz_sm + 3 * sz_hbf + sz_ebuf
                             + 2 * sz_np + 3 * sz_idx;
    const size_t need_copies = need_base + 2 * sz_idx + sz_xbf + sz_eabf;
    const size_t need_full   = need_copies + sz_hf;
    int mode = (ws_size >= need_full) ? 0 : (ws_size >= need_copies) ? 1 : 2;
    const bool hf32 = (mode == 0), copies = (mode <= 1);

    char* ws = (char*)d_ws;
    size_t off = 0;
    auto alloc = [&](size_t bytes) -> void* { void* p = ws + off; off += bytes; return p; };
    int*    flags  = (int*)alloc(sz_flags);
    ushort* wtpool = (ushort*)alloc(sz_wt);
    ushort* smalls = (ushort*)alloc(sz_sm);
    ushort* h_bf   = (ushort*)alloc(sz_hbf);
    ushort* hA     = (ushort*)alloc(sz_hbf);
    ushort* hB     = (ushort*)alloc(sz_hbf);
    ushort* ebuf   = (ushort*)alloc(sz_ebuf);
    int*    cnt    = (int*)alloc(sz_np);
    int*    rowptr = (int*)alloc(sz_np);
    int*    src_s  = (int*)alloc(sz_idx);
    int*    dst_s  = (int*)alloc(sz_idx);
    int*    eid    = (int*)alloc(sz_idx);
    const int* eidx = (const int*)d_in[1];
    int*    src32 = copies ? (int*)alloc(sz_idx) : (int*)eidx;
    int*    dst32 = copies ? (int*)alloc(sz_idx) : (int*)(eidx + E);
    ushort* x_bf  = copies ? (ushort*)alloc(sz_xbf)  : (ushort*)d_in[0];
    ushort* ea_bf = copies ? (ushort*)alloc(sz_eabf) : (ushort*)d_in[2];
    float*  h_f32 = hf32 ? (float*)alloc(sz_hf) : nullptr;

    SPk sp;
    const int soff[17] = {0, 576, 672, 768, 1536, 1632, 1728, 2112, 2496, 2880,
                          3264, 3360, 3456, 3552, 3648, 3649, 3650};
    for (int i = 0; i < 17; i++) sp.off[i] = soff[i];
    sp.src[0]  = d_in[3];   sp.src[1]  = d_in[4];   sp.src[2]  = d_in[6];
    sp.src[3]  = d_in[7];   sp.src[4]  = d_in[8];   sp.src[5]  = d_in[10];
    sp.src[6]  = d_in[12];  sp.src[7]  = d_in[14];  sp.src[8]  = d_in[16];
    sp.src[9]  = d_in[18];  sp.src[10] = d_in[20];  sp.src[11] = d_in[21];
    sp.src[12] = d_in[24];  sp.src[13] = d_in[25];  sp.src[14] = d_in[22];
    sp.src[15] = d_in[26];
    auto SM = [&](int o) { return smalls + o; };

    TPk tp; int q = 0;
    tp.base[q] = d_in[5];  tp.eloff[q++] = 0;
    tp.base[q] = d_in[9];  tp.eloff[q++] = 0;
    for (int l = 0; l < 4; l++) {
        tp.base[q] = d_in[11]; tp.eloff[q++] = l * 27648;
        tp.base[q] = d_in[11]; tp.eloff[q++] = l * 27648 + 9216;
        tp.base[q] = d_in[11]; tp.eloff[q++] = l * 27648 + 18432;
        tp.base[q] = d_in[13]; tp.eloff[q++] = l * 9216;
        tp.base[q] = d_in[15]; tp.eloff[q++] = l * 18432;
        tp.base[q] = d_in[15]; tp.eloff[q++] = l * 18432 + 9216;
        tp.base[q] = d_in[17]; tp.eloff[q++] = l * 9216;
    }
    tp.base[q] = d_in[23]; tp.eloff[q++] = 0;
    tp.base[q] = d_in[23]; tp.eloff[q++] = 9216;
    tp.base[q] = d_in[23]; tp.eloff[q++] = 18432;
    tp.base[q] = d_in[19]; tp.eloff[q++] = 0;
    auto WT = [&](int i) { return wtpool + (size_t)i * 9216; };

    const int nblkN = (N + 63) / 64;
    const int nblkE = (E + 63) / 64;
    const int ntilE128 = (E + 127) / 128;

    // ---- prep ----
    detect_kernel<<<1, 256, 0, stream>>>((const ushort*)d_in[0], (const uint*)d_in[1], flags);
    smalls_kernel<<<1, 256, 0, stream>>>(sp, smalls, flags);
    transpose_k<<<34, 256, 0, stream>>>(tp, wtpool, flags);
    if (copies) {
        idx_convert<<<1024, 256, 0, stream>>>(eidx, src32, dst32, flags, E);
        xe_convert<<<2048, 256, 0, stream>>>(d_in[0], d_in[2], x_bf, ea_bf, flags,
                                             (size_t)N * 6, (size_t)E * 8);
    }
    hipMemsetAsync(cnt, 0, (size_t)(N + 1) * 4, stream);
    hist_kernel<<<1024, 256, 0, stream>>>(dst32, cnt, E);
    prefix_kernel<<<1, 1024, 0, stream>>>(cnt, rowptr, N, E);
    scatter_kernel<<<1024, 256, 0, stream>>>(src32, dst32, cnt, src_s, dst_s, eid, E);

    // ---- encoders (edge encoder writes e in dst-sorted order) ----
    if (hf32)
        encoder_kernel<6, true><<<nblkN, 256, 0, stream>>>(x_bf, SM(0), SM(576), WT(0), SM(672), h_bf, h_f32, nullptr, N);
    else
        encoder_kernel<6, false><<<nblkN, 256, 0, stream>>>(x_bf, SM(0), SM(576), WT(0), SM(672), h_bf, nullptr, nullptr, N);
    encoder_kernel<8, false><<<nblkE, 256, 0, stream>>>(ea_bf, SM(768), SM(1536), WT(1), SM(1632), ebuf, nullptr, eid, E);

    // ---- message-passing layers ----
    for (int l = 0; l < 4; l++) {
        int b = 2 + l * 7;
        gemm_dual_kernel<<<nblkN, 256, 0, stream>>>(h_bf, WT(b + 0), WT(b + 1), hA, hB, N);
        int egrid = ntilE128 < 2048 ? ntilE128 : 2048;
        edge_layer_kernel<<<egrid, 512, 0, stream>>>(
            ebuf, hA, hB, src_s, dst_s, WT(b + 2), SM(1728 + l * 96),
            WT(b + 3), SM(2112 + l * 96), ntilE128, E);
        if (hf32)
            node_layer_kernel<true><<<nblkN, 256, 0, stream>>>(
                h_f32, h_bf, ebuf, rowptr, WT(b + 4), WT(b + 5), SM(2496 + l * 96),
                WT(b + 6), SM(2880 + l * 96), N);
        else
            node_layer_kernel<false><<<nblkN, 256, 0, stream>>>(
                nullptr, h_bf, ebuf, rowptr, WT(b + 4), WT(b + 5), SM(2496 + l * 96),
                WT(b + 6), SM(2880 + l * 96), N);
    }

    // ---- heads (FP32 output; edge head scatters to original edge order) ----
    gemm_dual_kernel<<<nblkN, 256, 0, stream>>>(h_bf, WT(30), WT(31), hA, hB, N);
    float* out = (float*)d_out;
    head_kernel<true><<<nblkE, 256, 0, stream>>>(
        ebuf, hA, hB, src_s, dst_s, WT(32), SM(3456), SM(3552), SM(3649), out, eid, E);
    head_kernel<false><<<nblkN, 256, 0, stream>>>(
        h_bf, nullptr, nullptr, nullptr, nullptr, WT(33), SM(3264), SM(3360), SM(3648), out + E, nullptr, N);
}